// Round 1
// 69.414 us; speedup vs baseline: 1.0118x; 1.0118x over previous
//
#include <hip/hip_runtime.h>

#define CIN 27
#define HH 64
#define WW 64
#define OC 32
#define TW 16            // tile width (pixels)
#define TH 16            // tile height (pixels)
#define RS 20            // LDS row stride (dwords). EVEN -> every compute row read is two
                         // aligned ds_read_b64; banks (20*ty+2*tx)%32 tile evenly (conflict-free)
#define CS (18 * RS)     // 360 dwords per channel slab
#define GC 9             // channels per partial block (27 = 3 x 9)
// LDS per block: 9*360*4 = 12960 B -> 12 blocks/CU (155.5 KB of 160 KB), 24 waves/CU

__device__ __forceinline__ float maj3(float a, float b, float c) {
    // Exact closed form of bipolar 3-input majority gate: (a + b + c - a*b*c)/2
    float s = a + b + c;
    return 0.5f * fmaf(-(a * b), c, s);
}

__device__ __forceinline__ float2 pk_maj3(float2 a, float2 b, float2 c) {
    float2 r;
    r.x = maj3(a.x, b.x, c.x);
    r.y = maj3(a.y, b.y, c.y);
    return r;
}

// ---------------------------------------------------------------------------
// Partial kernel: one block = one (tile, n, oc, q) where q indexes a 9-channel
// group. Computes the level-4 majority partial m4[q] for its 256-pixel tile.
// Bit-identical fp sequence to the fused kernel's inner q-iteration.
// ---------------------------------------------------------------------------
__global__ __launch_bounds__(128, 6) void sconv_partial_kernel(
    const float* __restrict__ x,    // [N, CIN, 64, 64]
    const float* __restrict__ wgt,  // [OC, CIN, 3, 3]
    float* __restrict__ part)       // [3, N, OC, 64, 64]
{
    __shared__ __align__(16) float sx[GC * CS];   // 12960 B

    const int tx = threadIdx.x;            // 0..7  (pixel cols 2tx, 2tx+1)
    const int ty = threadIdx.y;            // 0..15
    const int tid = ty * 8 + tx;
    const int tile_w0 = blockIdx.x * TW;
    const int tile_h0 = blockIdx.y * TH;
    const int z  = blockIdx.z;             // 0..191
    const int q  = z >> 6;                 // 0..2  channel-group
    const int n  = (z >> 5) & 1;
    const int oc = z & 31;
    const int c0 = q * GC;

    // ---- stage 9-channel x tile with 1-halo ----
    const float* xn = x + ((size_t)n * CIN + c0) * (HH * WW);
    for (int pos = tid; pos < 18 * 18; pos += 128) {
        int r   = pos / 18;
        int col = pos - 18 * r;
        int gr = tile_h0 + r - 1;
        int gc = tile_w0 + col - 1;
        bool ok = ((unsigned)gr < (unsigned)HH) & ((unsigned)gc < (unsigned)WW);
        int off = ok ? (gr * WW + gc) : 0;     // clamped addr, select after load
        float* lp = sx + r * RS + col;
        #pragma unroll
        for (int c = 0; c < GC; ++c) {
            float raw = xn[(size_t)c * (HH * WW) + off];
            lp[c * CS] = ok ? raw : 0.0f;
        }
    }
    __syncthreads();

    // Weights: block-uniform address -> compiler emits scalar loads (SGPRs),
    // zero LDS-pipe cost.
    const float* wp = wgt + ((size_t)oc * CIN + c0) * 9;

    // ---- 4-level majority sub-tree over 9 channels ----
    float2 m3[3];
    #pragma unroll
    for (int t = 0; t < 3; ++t) {          // level-3 group (3 channels each)
        float2 m2[3];
        #pragma unroll
        for (int u = 0; u < 3; ++u) {      // channel within triple
            const int c = t * 3 + u;
            float wk[9];
            #pragma unroll
            for (int k = 0; k < 9; ++k) wk[k] = wp[c * 9 + k];
            float2 m1[3];
            #pragma unroll
            for (int ki = 0; ki < 3; ++ki) {
                // base dword = c*360 + (ty+ki)*20 + 2tx : even -> two aligned b64
                const float2* prow =
                    (const float2*)&sx[c * CS + (ty + ki) * RS + 2 * tx];
                float2 v01 = prow[0];   // cols 2tx, 2tx+1
                float2 v23 = prow[1];   // cols 2tx+2, 2tx+3
                float w0 = wk[ki * 3 + 0];
                float w1 = wk[ki * 3 + 1];
                float w2 = wk[ki * 3 + 2];
                // pixel A (col 2tx): v01.x v01.y v23.x ; pixel B: v01.y v23.x v23.y
                float2 p0 = make_float2(v01.x * w0, v01.y * w0);
                float2 p1 = make_float2(v01.y * w1, v23.x * w1);
                float2 p2 = make_float2(v23.x * w2, v23.y * w2);
                m1[ki] = pk_maj3(p0, p1, p2);
            }
            m2[u] = pk_maj3(m1[0], m1[1], m1[2]);
        }
        m3[t] = pk_maj3(m2[0], m2[1], m2[2]);
    }
    float2 m4 = pk_maj3(m3[0], m3[1], m3[2]);

    const int h = tile_h0 + ty;
    const int w = tile_w0 + 2 * tx;
    float2* po = (float2*)(part + ((((size_t)q * 2 + n) * OC + oc) * HH + h) * WW + w);
    *po = m4;
}

// ---------------------------------------------------------------------------
// Combine kernel: out = maj3(p0, p1, p2) elementwise. 1 MB out, 3 MB in.
// ---------------------------------------------------------------------------
#define NPIX (2 * OC * HH * WW)   // 262144 floats

__global__ __launch_bounds__(256) void sconv_combine_kernel(
    const float* __restrict__ part,   // [3, N, OC, 64, 64]
    float* __restrict__ out)          // [N, OC, 64, 64]
{
    int i = blockIdx.x * 256 + threadIdx.x;        // over float4 groups (65536)
    const float4* p0 = (const float4*)part;
    const float4* p1 = (const float4*)(part + NPIX);
    const float4* p2 = (const float4*)(part + 2 * NPIX);
    float4 a = p0[i];
    float4 b = p1[i];
    float4 c = p2[i];
    float4 r;
    r.x = maj3(a.x, b.x, c.x);
    r.y = maj3(a.y, b.y, c.y);
    r.z = maj3(a.z, b.z, c.z);
    r.w = maj3(a.w, b.w, c.w);
    ((float4*)out)[i] = r;
}

extern "C" void kernel_launch(void* const* d_in, const int* in_sizes, int n_in,
                              void* d_out, int out_size, void* d_ws, size_t ws_size,
                              hipStream_t stream) {
    const float* x   = (const float*)d_in[0];
    const float* wgt = (const float*)d_in[1];
    float* out  = (float*)d_out;
    float* part = (float*)d_ws;                // 3 MB of workspace

    dim3 block(8, 16, 1);                      // 128 threads, 2 waves
    dim3 grid(WW / TW, HH / TH, 3 * 2 * OC);   // (4,4,192) = 3072 blocks, 12/CU resident
    sconv_partial_kernel<<<grid, block, 0, stream>>>(x, wgt, part);

    dim3 cblock(256, 1, 1);
    dim3 cgrid(NPIX / 4 / 256, 1, 1);          // 256 blocks
    sconv_combine_kernel<<<cgrid, cblock, 0, stream>>>(part, out);
}

// Round 2
// 68.683 us; speedup vs baseline: 1.0226x; 1.0106x over previous
//
#include <hip/hip_runtime.h>

#define CIN 27
#define HH 64
#define WW 64
#define OC 32
#define TW 16            // tile width (pixels)
#define TH 16            // tile height (pixels)
#define RS 20            // LDS row stride (dwords): mult-of-4 -> b128-aligned compute reads
#define CS (18 * RS)     // 360 dwords per channel slab
#define WS 12            // padded per-channel weight stride (48B, 16B-aligned)
// LDS: x 27*360*4 = 38880 B + weights 27*12*4 = 1296 B = 40176 B -> 4 blocks/CU.
// Partial-combine buffer (2*256 floats) is OVERLAID on sx after a barrier: no extra LDS.

__device__ __forceinline__ float maj3(float a, float b, float c) {
    // Exact closed form of bipolar 3-input majority gate: (a + b + c - a*b*c)/2
    float s = a + b + c;
    return 0.5f * fmaf(-(a * b), c, s);
}

// ---------------------------------------------------------------------------
// One block = one (16x16 tile, n, oc). 3 waves; wave q computes the 9-channel
// level-4 partial m4[q] for all 256 pixels (4 px per thread, row-contiguous),
// then partials are combined through LDS. FP sequence identical to reference
// folding order: products -> m1(ki) -> m2(u) -> m3(t) -> m4(q) -> maj3 across q.
// ---------------------------------------------------------------------------
__global__ __launch_bounds__(192, 3) void sconv_maj_kernel(
    const float* __restrict__ x,    // [N, CIN, 64, 64]
    const float* __restrict__ wgt,  // [OC, CIN, 3, 3]
    float* __restrict__ out)        // [N, OC, 64, 64]
{
    __shared__ __align__(16) float sw[CIN * WS];
    __shared__ __align__(16) float sx[CIN * CS];

    const int tx = threadIdx.x;            // 0..3   (pixel cols 4tx .. 4tx+3)
    const int ty = threadIdx.y;            // 0..15  (pixel row)
    const int q  = threadIdx.z;            // 0..2   (channel group, one wave each)
    const int tid = tx + 4 * (ty + 16 * q);   // 0..191; each z-slice = one wave
    const int tile_w0 = blockIdx.x * TW;
    const int tile_h0 = blockIdx.y * TH;
    const int n  = blockIdx.z >> 5;        // OC = 32
    const int oc = blockIdx.z & 31;

    // ---- stage weights (block-uniform oc) into padded LDS slots ----
    for (int i = tid; i < CIN * 9; i += 192) {
        int c = i / 9;
        int k = i - 9 * c;
        sw[c * WS + k] = wgt[oc * (CIN * 9) + i];
    }

    // ---- stage x tile with 1-halo (single pass, all 27 channels) ----
    const float* xn = x + (size_t)n * (CIN * HH * WW);
    for (int pos = tid; pos < 18 * 18; pos += 192) {
        int r   = pos / 18;
        int col = pos - 18 * r;
        int gr = tile_h0 + r - 1;
        int gc = tile_w0 + col - 1;
        bool ok = ((unsigned)gr < (unsigned)HH) & ((unsigned)gc < (unsigned)WW);
        int off = ok ? (gr * WW + gc) : 0;     // clamped addr, select after load
        float* lp = sx + r * RS + col;
        #pragma unroll
        for (int c = 0; c < CIN; ++c) {
            float raw = xn[(size_t)c * (HH * WW) + off];
            lp[c * CS] = ok ? raw : 0.0f;
        }
    }
    __syncthreads();

    // ---- wave q: 4-level majority sub-tree over channels q*9 .. q*9+8 ----
    const int c0 = q * 9;
    float m3_[3][4];
    #pragma unroll
    for (int t = 0; t < 3; ++t) {
        float m2_[3][4];
        #pragma unroll
        for (int u = 0; u < 3; ++u) {
            const int c = c0 + t * 3 + u;
            float4 wa = *(const float4*)&sw[c * WS];      // w0..w3 (broadcast)
            float4 wb = *(const float4*)&sw[c * WS + 4];  // w4..w7
            float  w8 = sw[c * WS + 8];
            const float wk[9] = {wa.x, wa.y, wa.z, wa.w,
                                 wb.x, wb.y, wb.z, wb.w, w8};
            float m1_[3][4];
            #pragma unroll
            for (int ki = 0; ki < 3; ++ki) {
                // base dword = c*360 + (ty+ki)*20 + 4tx : mult-of-4 -> b128 + b64
                const float* prow = &sx[c * CS + (ty + ki) * RS + 4 * tx];
                float4 v4 = *(const float4*)prow;         // cols 4tx .. 4tx+3
                float2 v2 = *(const float2*)(prow + 4);   // cols 4tx+4, 4tx+5
                const float in6[6] = {v4.x, v4.y, v4.z, v4.w, v2.x, v2.y};
                float w0 = wk[ki * 3 + 0];
                float w1 = wk[ki * 3 + 1];
                float w2 = wk[ki * 3 + 2];
                #pragma unroll
                for (int j = 0; j < 4; ++j) {
                    // pixel (ty, 4tx+j): inputs in6[j], in6[j+1], in6[j+2]
                    m1_[ki][j] = maj3(in6[j] * w0, in6[j + 1] * w1, in6[j + 2] * w2);
                }
            }
            #pragma unroll
            for (int j = 0; j < 4; ++j)
                m2_[u][j] = maj3(m1_[0][j], m1_[1][j], m1_[2][j]);
        }
        #pragma unroll
        for (int j = 0; j < 4; ++j)
            m3_[t][j] = maj3(m2_[0][j], m2_[1][j], m2_[2][j]);
    }
    float m4_[4];
    #pragma unroll
    for (int j = 0; j < 4; ++j)
        m4_[j] = maj3(m3_[0][j], m3_[1][j], m3_[2][j]);

    // ---- combine the three wave-partials through LDS (overlaid on sx) ----
    __syncthreads();                       // all sx/sw reads complete
    float* sp = sx;                        // [2][256] floats, reuse x slab
    const int px = ty * TW + 4 * tx;       // pixel index within tile
    if (q > 0)
        *(float4*)&sp[(q - 1) * 256 + px] =
            make_float4(m4_[0], m4_[1], m4_[2], m4_[3]);
    __syncthreads();

    if (q == 0) {
        float4 b = *(const float4*)&sp[px];        // m4[1]
        float4 c = *(const float4*)&sp[256 + px];  // m4[2]
        float4 r;
        r.x = maj3(m4_[0], b.x, c.x);
        r.y = maj3(m4_[1], b.y, c.y);
        r.z = maj3(m4_[2], b.z, c.z);
        r.w = maj3(m4_[3], b.w, c.w);
        const int h = tile_h0 + ty;
        const int w = tile_w0 + 4 * tx;
        *(float4*)(out + (((size_t)n * OC + oc) * HH + h) * WW + w) = r;
    }
}

extern "C" void kernel_launch(void* const* d_in, const int* in_sizes, int n_in,
                              void* d_out, int out_size, void* d_ws, size_t ws_size,
                              hipStream_t stream) {
    const float* x   = (const float*)d_in[0];
    const float* wgt = (const float*)d_in[1];
    float* out = (float*)d_out;

    dim3 block(4, 16, 3);                 // 192 threads = 3 waves (one per q-group)
    dim3 grid(WW / TW, HH / TH, 2 * OC);  // (4,4,64) = 1024 blocks, 4/CU resident
    sconv_maj_kernel<<<grid, block, 0, stream>>>(x, wgt, out);
}